// Round 1
// baseline (618.517 us; speedup 1.0000x reference)
//
#include <hip/hip_runtime.h>
#include <math.h>

#define NPTS 500000
#define M_ASSIGN 400000
#define WPR 15625  // 500000/32 words per bitmap row

// workspace layout (float units)
constexpr int OFF_ACC     = 0;        // [0]=nll_sum [1]=valid_cnt [2]=l1_sum [3]=cos_sum [4]=mask_sum
constexpr int OFF_SUM     = 64;       // 64 BN sums
constexpr int OFF_SQ      = 128;      // 64 BN sumsq
constexpr int OFF_SCALE   = 192;      // 64
constexpr int OFF_SHIFT   = 256;      // 64
constexpr int OFF_BITMAP  = 320;      // 2,000,000 uint32
constexpr int OFF_SEGPRED = 2000320;  // 500,000 int
constexpr int OFF_INSTPRED= 2500320;  // 128 int
constexpr int OFF_PROBS   = 2500448;  // 10,000,000 float (byte offset 16B-aligned)

__global__ __launch_bounds__(256) void pass_a_kernel(
    const float* __restrict__ feat, const float* __restrict__ w1,
    const float* __restrict__ b1, const float* __restrict__ seg_w,
    const float* __restrict__ seg_b, const int* __restrict__ segment,
    float* __restrict__ ws)
{
  __shared__ __align__(16) float w1s[4096];
  __shared__ __align__(16) float sws[1280];
  __shared__ __align__(16) float b1s[64];
  __shared__ __align__(16) float sbs[20];
  __shared__ float lsum[64];
  __shared__ float lsq[64];
  __shared__ float rn[4], rv[4];

  float* acc  = ws + OFF_ACC;
  float* gsum = ws + OFF_SUM;
  float* gsq  = ws + OFF_SQ;
  int*   segp = (int*)(ws + OFF_SEGPRED);
  float* probs= ws + OFF_PROBS;

  const int tid = threadIdx.x;
  for (int i = tid; i < 4096; i += 256) w1s[i] = w1[i];
  for (int i = tid; i < 1280; i += 256) sws[i] = seg_w[i];
  if (tid < 64) { b1s[tid] = b1[tid]; lsum[tid] = 0.f; lsq[tid] = 0.f; }
  if (tid < 20) sbs[tid] = seg_b[tid];
  __syncthreads();

  const int n = blockIdx.x * 256 + tid;
  float nll = 0.f, vld = 0.f;
  if (n < NPTS) {
    float f[64];
    const float4* fr = (const float4*)(feat + (size_t)n * 64);
    #pragma unroll
    for (int i = 0; i < 16; ++i) {
      float4 v = fr[i];
      f[4*i+0] = v.x; f[4*i+1] = v.y; f[4*i+2] = v.z; f[4*i+3] = v.w;
    }
    const int lane = tid & 63;
    for (int cg = 0; cg < 16; ++cg) {
      const int c0 = 4 * ((cg + lane) & 15);
      float4 hv = *(const float4*)&b1s[c0];
      #pragma unroll
      for (int k = 0; k < 64; ++k) {
        const float fk = f[k];
        const float4 w = *(const float4*)&w1s[k * 64 + c0];
        hv.x = fmaf(fk, w.x, hv.x);
        hv.y = fmaf(fk, w.y, hv.y);
        hv.z = fmaf(fk, w.z, hv.z);
        hv.w = fmaf(fk, w.w, hv.w);
      }
      atomicAdd(&lsum[c0+0], hv.x); atomicAdd(&lsq[c0+0], hv.x*hv.x);
      atomicAdd(&lsum[c0+1], hv.y); atomicAdd(&lsq[c0+1], hv.y*hv.y);
      atomicAdd(&lsum[c0+2], hv.z); atomicAdd(&lsq[c0+2], hv.z*hv.z);
      atomicAdd(&lsum[c0+3], hv.w); atomicAdd(&lsq[c0+3], hv.w*hv.w);
    }
    float4 a0 = *(const float4*)&sbs[0];
    float4 a1 = *(const float4*)&sbs[4];
    float4 a2 = *(const float4*)&sbs[8];
    float4 a3 = *(const float4*)&sbs[12];
    float4 a4 = *(const float4*)&sbs[16];
    #pragma unroll
    for (int k = 0; k < 64; ++k) {
      const float fk = f[k];
      const float4 s0 = *(const float4*)&sws[k*20+0];
      const float4 s1 = *(const float4*)&sws[k*20+4];
      const float4 s2 = *(const float4*)&sws[k*20+8];
      const float4 s3 = *(const float4*)&sws[k*20+12];
      const float4 s4 = *(const float4*)&sws[k*20+16];
      a0.x = fmaf(fk, s0.x, a0.x); a0.y = fmaf(fk, s0.y, a0.y); a0.z = fmaf(fk, s0.z, a0.z); a0.w = fmaf(fk, s0.w, a0.w);
      a1.x = fmaf(fk, s1.x, a1.x); a1.y = fmaf(fk, s1.y, a1.y); a1.z = fmaf(fk, s1.z, a1.z); a1.w = fmaf(fk, s1.w, a1.w);
      a2.x = fmaf(fk, s2.x, a2.x); a2.y = fmaf(fk, s2.y, a2.y); a2.z = fmaf(fk, s2.z, a2.z); a2.w = fmaf(fk, s2.w, a2.w);
      a3.x = fmaf(fk, s3.x, a3.x); a3.y = fmaf(fk, s3.y, a3.y); a3.z = fmaf(fk, s3.z, a3.z); a3.w = fmaf(fk, s3.w, a3.w);
      a4.x = fmaf(fk, s4.x, a4.x); a4.y = fmaf(fk, s4.y, a4.y); a4.z = fmaf(fk, s4.z, a4.z); a4.w = fmaf(fk, s4.w, a4.w);
    }
    float lg[20];
    lg[0]=a0.x; lg[1]=a0.y; lg[2]=a0.z; lg[3]=a0.w;
    lg[4]=a1.x; lg[5]=a1.y; lg[6]=a1.z; lg[7]=a1.w;
    lg[8]=a2.x; lg[9]=a2.y; lg[10]=a2.z; lg[11]=a2.w;
    lg[12]=a3.x; lg[13]=a3.y; lg[14]=a3.z; lg[15]=a3.w;
    lg[16]=a4.x; lg[17]=a4.y; lg[18]=a4.z; lg[19]=a4.w;

    const int seg = segment[n];
    const bool valid = (seg != -1);
    const int sidx = seg < 0 ? 0 : (seg > 19 ? 19 : seg);
    float m = lg[0]; int bi = 0;
    #pragma unroll
    for (int j = 1; j < 20; ++j) { if (lg[j] > m) { m = lg[j]; bi = j; } }
    float lsv = lg[0];
    #pragma unroll
    for (int j = 1; j < 20; ++j) lsv = (j == sidx) ? lg[j] : lsv;
    float se = 0.f;
    #pragma unroll
    for (int j = 0; j < 20; ++j) { lg[j] = __expf(lg[j] - m); se += lg[j]; }
    const float inv = 1.f / se;
    float4* pr = (float4*)(probs + (size_t)n * 20);
    pr[0] = make_float4(lg[0]*inv,  lg[1]*inv,  lg[2]*inv,  lg[3]*inv);
    pr[1] = make_float4(lg[4]*inv,  lg[5]*inv,  lg[6]*inv,  lg[7]*inv);
    pr[2] = make_float4(lg[8]*inv,  lg[9]*inv,  lg[10]*inv, lg[11]*inv);
    pr[3] = make_float4(lg[12]*inv, lg[13]*inv, lg[14]*inv, lg[15]*inv);
    pr[4] = make_float4(lg[16]*inv, lg[17]*inv, lg[18]*inv, lg[19]*inv);
    segp[n] = bi;
    nll = valid ? (m + __logf(se) - lsv) : 0.f;
    vld = valid ? 1.f : 0.f;
  }
  #pragma unroll
  for (int o = 32; o > 0; o >>= 1) {
    nll += __shfl_down(nll, o);
    vld += __shfl_down(vld, o);
  }
  if ((tid & 63) == 0) { rn[tid >> 6] = nll; rv[tid >> 6] = vld; }
  __syncthreads();
  if (tid == 0) {
    atomicAdd(&acc[0], rn[0]+rn[1]+rn[2]+rn[3]);
    atomicAdd(&acc[1], rv[0]+rv[1]+rv[2]+rv[3]);
  }
  if (tid < 64) { atomicAdd(&gsum[tid], lsum[tid]); atomicAdd(&gsq[tid], lsq[tid]); }
}

__global__ void bn_kernel(const float* __restrict__ gamma, const float* __restrict__ beta,
                          const float* __restrict__ b1, float* __restrict__ ws)
{
  const int c = threadIdx.x;  // 64 threads
  const float mu  = ws[OFF_SUM + c] * (1.f / NPTS);
  const float var = ws[OFF_SQ  + c] * (1.f / NPTS) - mu * mu;
  const float s = gamma[c] * rsqrtf(var + 0.001f);
  ws[OFF_SCALE + c] = s;
  ws[OFF_SHIFT + c] = beta[c] + (b1[c] - mu) * s;
}

__global__ __launch_bounds__(256) void pass_c_kernel(
    const float* __restrict__ feat, const float* __restrict__ w1,
    const float* __restrict__ coord, const float* __restrict__ cent,
    const float* __restrict__ w2, const float* __restrict__ b2,
    const int* __restrict__ instance, float* __restrict__ ws)
{
  __shared__ __align__(16) float w1s[4096];
  __shared__ __align__(16) float w2s[256];
  __shared__ float scs[64], shs[64];
  __shared__ float r0[4], r1[4], r2[4];

  float* acc = ws + OFF_ACC;
  const int tid = threadIdx.x;
  for (int i = tid; i < 4096; i += 256) w1s[i] = w1[i];
  if (tid < 64) {
    w2s[tid*4+0] = w2[tid*3+0];
    w2s[tid*4+1] = w2[tid*3+1];
    w2s[tid*4+2] = w2[tid*3+2];
    w2s[tid*4+3] = 0.f;
    scs[tid] = ws[OFF_SCALE + tid];
    shs[tid] = ws[OFF_SHIFT + tid];
  }
  __syncthreads();

  const int n = blockIdx.x * 256 + tid;
  float l1v = 0.f, cosv = 0.f, mk = 0.f;
  if (n < NPTS) {
    float f[64];
    const float4* fr = (const float4*)(feat + (size_t)n * 64);
    #pragma unroll
    for (int i = 0; i < 16; ++i) {
      float4 v = fr[i];
      f[4*i+0] = v.x; f[4*i+1] = v.y; f[4*i+2] = v.z; f[4*i+3] = v.w;
    }
    float bx = b2[0], by = b2[1], bz = b2[2];
    const int lane = tid & 63;
    for (int cg = 0; cg < 16; ++cg) {
      const int c0 = 4 * ((cg + lane) & 15);
      float4 hv = make_float4(0.f, 0.f, 0.f, 0.f);
      #pragma unroll
      for (int k = 0; k < 64; ++k) {
        const float fk = f[k];
        const float4 w = *(const float4*)&w1s[k * 64 + c0];
        hv.x = fmaf(fk, w.x, hv.x);
        hv.y = fmaf(fk, w.y, hv.y);
        hv.z = fmaf(fk, w.z, hv.z);
        hv.w = fmaf(fk, w.w, hv.w);
      }
      const float h0 = fmaxf(fmaf(hv.x, scs[c0+0], shs[c0+0]), 0.f);
      const float h1 = fmaxf(fmaf(hv.y, scs[c0+1], shs[c0+1]), 0.f);
      const float h2 = fmaxf(fmaf(hv.z, scs[c0+2], shs[c0+2]), 0.f);
      const float h3 = fmaxf(fmaf(hv.w, scs[c0+3], shs[c0+3]), 0.f);
      const float4 wv0 = *(const float4*)&w2s[(c0+0)*4];
      const float4 wv1 = *(const float4*)&w2s[(c0+1)*4];
      const float4 wv2 = *(const float4*)&w2s[(c0+2)*4];
      const float4 wv3 = *(const float4*)&w2s[(c0+3)*4];
      bx = fmaf(h0, wv0.x, bx); by = fmaf(h0, wv0.y, by); bz = fmaf(h0, wv0.z, bz);
      bx = fmaf(h1, wv1.x, bx); by = fmaf(h1, wv1.y, by); bz = fmaf(h1, wv1.z, bz);
      bx = fmaf(h2, wv2.x, bx); by = fmaf(h2, wv2.y, by); bz = fmaf(h2, wv2.z, bz);
      bx = fmaf(h3, wv3.x, bx); by = fmaf(h3, wv3.y, by); bz = fmaf(h3, wv3.z, bz);
    }
    const float cx = coord[(size_t)n*3+0], cy = coord[(size_t)n*3+1], cz = coord[(size_t)n*3+2];
    const float ex = cent[(size_t)n*3+0],  ey = cent[(size_t)n*3+1],  ez = cent[(size_t)n*3+2];
    const float gx = ex - cx, gy = ey - cy, gz = ez - cz;
    const float dx = bx - gx, dy = by - gy, dz = bz - gz;
    const float l1 = fabsf(dx) + fabsf(dy) + fabsf(dz);
    const float npn = sqrtf(bx*bx + by*by + bz*bz) + 1e-8f;
    const float ngn = sqrtf(gx*gx + gy*gy + gz*gz) + 1e-8f;
    const float cv = -(bx*gx + by*gy + bz*gz) / (npn * ngn);
    const int inst = instance[n];
    mk = (inst != -1) ? 1.f : 0.f;
    l1v = l1 * mk;
    cosv = cv * mk;
  }
  #pragma unroll
  for (int o = 32; o > 0; o >>= 1) {
    l1v  += __shfl_down(l1v, o);
    cosv += __shfl_down(cosv, o);
    mk   += __shfl_down(mk, o);
  }
  if ((tid & 63) == 0) { r0[tid>>6] = l1v; r1[tid>>6] = cosv; r2[tid>>6] = mk; }
  __syncthreads();
  if (tid == 0) {
    atomicAdd(&acc[2], r0[0]+r0[1]+r0[2]+r0[3]);
    atomicAdd(&acc[3], r1[0]+r1[1]+r1[2]+r1[3]);
    atomicAdd(&acc[4], r2[0]+r2[1]+r2[2]+r2[3]);
  }
}

__global__ __launch_bounds__(256) void assign_kernel(
    const int* __restrict__ prop_ids, const int* __restrict__ point_ids, float* __restrict__ ws)
{
  unsigned* bitmap = (unsigned*)(ws + OFF_BITMAP);
  const int i = blockIdx.x * 256 + threadIdx.x;
  if (i < M_ASSIGN) {
    const int p = prop_ids[i];
    const int n = point_ids[i];
    atomicOr(&bitmap[p * WPR + (n >> 5)], 1u << (n & 31));
  }
}

__global__ void first_kernel(const int* __restrict__ prop_ids, const int* __restrict__ point_ids,
                             float* __restrict__ ws)
{
  const int p = threadIdx.x;  // 128 threads
  int lo = 0, hi = M_ASSIGN;
  while (lo < hi) { const int mid = (lo + hi) >> 1; if (prop_ids[mid] < p) lo = mid + 1; else hi = mid; }
  if (lo > M_ASSIGN - 1) lo = M_ASSIGN - 1;
  const int* segp = (const int*)(ws + OFF_SEGPRED);
  int* ip = (int*)(ws + OFF_INSTPRED);
  ip[p] = segp[point_ids[lo]];
}

__global__ __launch_bounds__(256) void score_kernel(const float* __restrict__ ws, float* __restrict__ out)
{
  const unsigned* bitmap = (const unsigned*)(ws + OFF_BITMAP);
  const float* probs = ws + OFF_PROBS;
  const int* ip = (const int*)(ws + OFF_INSTPRED);
  __shared__ float rs[4];
  __shared__ int rc[4];
  const int p = blockIdx.x;
  const int cp = ip[p];
  const int tid = threadIdx.x;
  float s = 0.f; int cnt = 0;
  for (int w = tid; w < WPR; w += 256) {
    unsigned bits = bitmap[p * WPR + w];
    cnt += __popc(bits);
    while (bits) {
      const int b = __ffs(bits) - 1;
      bits &= bits - 1;
      const int n = (w << 5) + b;
      s += probs[(size_t)n * 20 + cp];
    }
  }
  #pragma unroll
  for (int o = 32; o > 0; o >>= 1) { s += __shfl_down(s, o); cnt += __shfl_down(cnt, o); }
  if ((tid & 63) == 0) { rs[tid>>6] = s; rc[tid>>6] = cnt; }
  __syncthreads();
  if (tid == 0) {
    const float st = rs[0]+rs[1]+rs[2]+rs[3];
    const int ct = rc[0]+rc[1]+rc[2]+rc[3];
    const bool mk = ct > 100;
    out[1 + p]   = mk ? st / (float)(ct > 1 ? ct : 1) : 0.f;
    out[129 + p] = mk ? 1.f : 0.f;
  }
}

__global__ void final_kernel(const float* __restrict__ ws, float* __restrict__ out)
{
  const float segl = ws[0] / fmaxf(ws[1], 1.f);
  const float d = ws[4] + 1e-8f;
  out[0] = segl + ws[2] / d + ws[3] / d;
}

extern "C" void kernel_launch(void* const* d_in, const int* in_sizes, int n_in,
                              void* d_out, int out_size, void* d_ws, size_t ws_size,
                              hipStream_t stream) {
  const float* feat    = (const float*)d_in[0];
  const float* coord   = (const float*)d_in[1];
  const float* cent    = (const float*)d_in[2];
  const float* w1      = (const float*)d_in[3];
  const float* b1      = (const float*)d_in[4];
  const float* gamma   = (const float*)d_in[5];
  const float* beta    = (const float*)d_in[6];
  const float* w2      = (const float*)d_in[7];
  const float* b2      = (const float*)d_in[8];
  const float* seg_w   = (const float*)d_in[9];
  const float* seg_b   = (const float*)d_in[10];
  const int* segment   = (const int*)d_in[11];
  const int* instance  = (const int*)d_in[12];
  const int* prop_ids  = (const int*)d_in[13];
  const int* point_ids = (const int*)d_in[14];
  float* out = (float*)d_out;
  float* ws  = (float*)d_ws;

  hipMemsetAsync(d_ws, 0, (size_t)(OFF_BITMAP + 2000000) * sizeof(float), stream);

  pass_a_kernel<<<1954, 256, 0, stream>>>(feat, w1, b1, seg_w, seg_b, segment, ws);
  bn_kernel<<<1, 64, 0, stream>>>(gamma, beta, b1, ws);
  pass_c_kernel<<<1954, 256, 0, stream>>>(feat, w1, coord, cent, w2, b2, instance, ws);
  assign_kernel<<<1563, 256, 0, stream>>>(prop_ids, point_ids, ws);
  first_kernel<<<1, 128, 0, stream>>>(prop_ids, point_ids, ws);
  score_kernel<<<128, 256, 0, stream>>>(ws, out);
  final_kernel<<<1, 1, 0, stream>>>(ws, out);
}

// Round 2
// 410.594 us; speedup vs baseline: 1.5064x; 1.5064x over previous
//
#include <hip/hip_runtime.h>
#include <math.h>

#define NPTS 500000
#define M_ASSIGN 400000
#define WPR 15625  // 500000/32 words per bitmap row

// workspace layout (float units)
constexpr int    OFF_ACC      = 0;        // [0]=nll_sum [1]=valid_cnt [2]=l1_sum [3]=cos_sum [4]=mask_sum
constexpr int    OFF_SUM      = 64;       // 64 BN sums (of raw h, no b1)
constexpr int    OFF_SQ       = 128;      // 64 BN sumsq
constexpr int    OFF_SCALE    = 192;      // 64
constexpr int    OFF_SHIFT    = 256;      // 64
constexpr int    OFF_BITMAP   = 320;      // 2,000,000 uint32
constexpr int    OFF_SEGPRED  = 2000320;  // 500,000 int
constexpr int    OFF_INSTPRED = 2500320;  // 128 int
constexpr int    OFF_PROBS    = 2500448;  // 10,000,000 float
constexpr size_t OFF_H        = 12500448; // 16,000,000 bf16 (8,000,000 float slots)

__device__ inline unsigned bf16rne(float x) {
  unsigned u = __float_as_uint(x);
  return (u + 0x7fffu + ((u >> 16) & 1u)) >> 16;
}
__device__ inline unsigned pack2bf16(float a, float b) {
  return bf16rne(a) | (bf16rne(b) << 16);
}

// ---------------------------------------------------------------------------
// K1: per-point fused  h-raw = feat@w1 (stored bf16),  logits = feat@seg_w+b,
//     softmax -> probs, argmax -> segp, NLL partials.
// Weights are read with block-uniform addresses -> scalar (SGPR) loads, no LDS.
// ---------------------------------------------------------------------------
__global__ __launch_bounds__(256) void fused_a_kernel(
    const float* __restrict__ feat, const float* __restrict__ w1,
    const float* __restrict__ seg_w, const float* __restrict__ seg_b,
    const int* __restrict__ segment, float* __restrict__ ws)
{
  __shared__ float rn[4], rv[4];
  float* acc  = ws + OFF_ACC;
  int*   segp = (int*)(ws + OFF_SEGPRED);
  float* probs = ws + OFF_PROBS;
  unsigned short* hbuf = (unsigned short*)(ws + OFF_H);

  const int tid = threadIdx.x;
  const int n = blockIdx.x * 256 + tid;
  float nll = 0.f, vld = 0.f;

  if (n < NPTS) {
    float hacc[64];
    #pragma unroll
    for (int c = 0; c < 64; ++c) hacc[c] = 0.f;
    float sacc[20];
    #pragma unroll
    for (int j = 0; j < 20; ++j) sacc[j] = seg_b[j];

    const float4* fr = (const float4*)(feat + (size_t)n * 64);
    for (int k4 = 0; k4 < 16; ++k4) {
      const float4 fv = fr[k4];
      const float fx[4] = {fv.x, fv.y, fv.z, fv.w};
      #pragma unroll
      for (int j = 0; j < 4; ++j) {
        const float fk = fx[j];
        const float* wr = w1 + (k4 * 4 + j) * 64;     // uniform address -> s_load
        #pragma unroll
        for (int c = 0; c < 64; ++c) hacc[c] = fmaf(fk, wr[c], hacc[c]);
        const float* sr = seg_w + (k4 * 4 + j) * 20;  // uniform address -> s_load
        #pragma unroll
        for (int c = 0; c < 20; ++c) sacc[c] = fmaf(fk, sr[c], sacc[c]);
      }
    }

    // store raw h as bf16 (RNE), 128B per point
    uint4* hv4 = (uint4*)(hbuf + (size_t)n * 64);
    #pragma unroll
    for (int i = 0; i < 8; ++i) {
      uint4 v;
      v.x = pack2bf16(hacc[8 * i + 0], hacc[8 * i + 1]);
      v.y = pack2bf16(hacc[8 * i + 2], hacc[8 * i + 3]);
      v.z = pack2bf16(hacc[8 * i + 4], hacc[8 * i + 5]);
      v.w = pack2bf16(hacc[8 * i + 6], hacc[8 * i + 7]);
      hv4[i] = v;
    }

    // softmax / argmax / nll over 20 logits (in registers)
    const int seg = segment[n];
    const bool valid = (seg != -1);
    const int sidx = seg < 0 ? 0 : (seg > 19 ? 19 : seg);
    float m = sacc[0]; int bi = 0;
    #pragma unroll
    for (int j = 1; j < 20; ++j) { if (sacc[j] > m) { m = sacc[j]; bi = j; } }
    float lsv = sacc[0];
    #pragma unroll
    for (int j = 1; j < 20; ++j) lsv = (j == sidx) ? sacc[j] : lsv;
    float se = 0.f;
    #pragma unroll
    for (int j = 0; j < 20; ++j) { sacc[j] = __expf(sacc[j] - m); se += sacc[j]; }
    const float inv = 1.f / se;
    float4* pr = (float4*)(probs + (size_t)n * 20);
    pr[0] = make_float4(sacc[0]*inv,  sacc[1]*inv,  sacc[2]*inv,  sacc[3]*inv);
    pr[1] = make_float4(sacc[4]*inv,  sacc[5]*inv,  sacc[6]*inv,  sacc[7]*inv);
    pr[2] = make_float4(sacc[8]*inv,  sacc[9]*inv,  sacc[10]*inv, sacc[11]*inv);
    pr[3] = make_float4(sacc[12]*inv, sacc[13]*inv, sacc[14]*inv, sacc[15]*inv);
    pr[4] = make_float4(sacc[16]*inv, sacc[17]*inv, sacc[18]*inv, sacc[19]*inv);
    segp[n] = bi;
    nll = valid ? (m + __logf(se) - lsv) : 0.f;
    vld = valid ? 1.f : 0.f;
  }

  #pragma unroll
  for (int o = 32; o > 0; o >>= 1) {
    nll += __shfl_down(nll, o);
    vld += __shfl_down(vld, o);
  }
  if ((tid & 63) == 0) { rn[tid >> 6] = nll; rv[tid >> 6] = vld; }
  __syncthreads();
  if (tid == 0) {
    atomicAdd(&acc[0], rn[0] + rn[1] + rn[2] + rn[3]);
    atomicAdd(&acc[1], rv[0] + rv[1] + rv[2] + rv[3]);
  }
}

// ---------------------------------------------------------------------------
// K2: per-channel sum / sumsq of bf16 h (coalesced column reduction)
// ---------------------------------------------------------------------------
__global__ __launch_bounds__(256) void stats_kernel(float* __restrict__ ws)
{
  const unsigned short* hbuf = (const unsigned short*)(ws + OFF_H);
  __shared__ float ls[256][9];
  __shared__ float lq[256][9];
  const int tid = threadIdx.x;
  const int g = tid & 7;    // channel group: channels g*8 .. g*8+7
  const int r = tid >> 3;   // row within 32-row tile

  float s[8], q[8];
  #pragma unroll
  for (int i = 0; i < 8; ++i) { s[i] = 0.f; q[i] = 0.f; }

  for (int rg = blockIdx.x; rg < 15625; rg += gridDim.x) {
    const int p = rg * 32 + r;
    const uint4 v = *(const uint4*)(hbuf + (size_t)p * 64 + g * 8);
    const unsigned uu[4] = {v.x, v.y, v.z, v.w};
    #pragma unroll
    for (int i = 0; i < 4; ++i) {
      const float lo = __uint_as_float(uu[i] << 16);
      const float hi = __uint_as_float(uu[i] & 0xffff0000u);
      s[2*i]   += lo; q[2*i]   += lo * lo;
      s[2*i+1] += hi; q[2*i+1] += hi * hi;
    }
  }
  #pragma unroll
  for (int i = 0; i < 8; ++i) { ls[tid][i] = s[i]; lq[tid][i] = q[i]; }
  __syncthreads();
  if (tid < 64) {
    const int c = tid;
    const int g2 = c >> 3, i2 = c & 7;
    float ts = 0.f, tq = 0.f;
    for (int r2 = 0; r2 < 32; ++r2) {
      ts += ls[r2 * 8 + g2][i2];
      tq += lq[r2 * 8 + g2][i2];
    }
    atomicAdd(&ws[OFF_SUM + c], ts);
    atomicAdd(&ws[OFF_SQ + c], tq);
  }
}

__global__ void bn_kernel(const float* __restrict__ gamma, const float* __restrict__ beta,
                          float* __restrict__ ws)
{
  const int c = threadIdx.x;  // 64 threads
  const float mu  = ws[OFF_SUM + c] * (1.f / NPTS);
  const float var = ws[OFF_SQ  + c] * (1.f / NPTS) - mu * mu;
  const float sc = gamma[c] * rsqrtf(var + 0.001f);
  ws[OFF_SCALE + c] = sc;
  ws[OFF_SHIFT + c] = beta[c] - mu * sc;   // b1 cancels through BN
}

// ---------------------------------------------------------------------------
// K3: read h bf16, apply BN+ReLU, bias head via w2, L1 + cosine loss partials
// ---------------------------------------------------------------------------
__global__ __launch_bounds__(256) void bias_loss_kernel(
    const float* __restrict__ coord, const float* __restrict__ cent,
    const float* __restrict__ w2, const float* __restrict__ b2,
    const int* __restrict__ instance, float* __restrict__ ws)
{
  __shared__ float r0[4], r1[4], r2[4];
  float* acc = ws + OFF_ACC;
  const unsigned short* hbuf = (const unsigned short*)(ws + OFF_H);
  const float* scale = ws + OFF_SCALE;
  const float* shift = ws + OFF_SHIFT;

  const int tid = threadIdx.x;
  const int n = blockIdx.x * 256 + tid;
  float l1v = 0.f, cosv = 0.f, mk = 0.f;
  if (n < NPTS) {
    float bx = b2[0], by = b2[1], bz = b2[2];
    const uint4* hv = (const uint4*)(hbuf + (size_t)n * 64);
    #pragma unroll
    for (int i = 0; i < 8; ++i) {
      const uint4 v = hv[i];
      const unsigned uu[4] = {v.x, v.y, v.z, v.w};
      #pragma unroll
      for (int j = 0; j < 4; ++j) {
        const int c = i * 8 + j * 2;
        const float lo = __uint_as_float(uu[j] << 16);
        const float hi = __uint_as_float(uu[j] & 0xffff0000u);
        const float h0 = fmaxf(fmaf(lo, scale[c],     shift[c]),     0.f);
        const float h1 = fmaxf(fmaf(hi, scale[c + 1], shift[c + 1]), 0.f);
        bx = fmaf(h0, w2[c * 3 + 0], bx);
        by = fmaf(h0, w2[c * 3 + 1], by);
        bz = fmaf(h0, w2[c * 3 + 2], bz);
        bx = fmaf(h1, w2[c * 3 + 3], bx);
        by = fmaf(h1, w2[c * 3 + 4], by);
        bz = fmaf(h1, w2[c * 3 + 5], bz);
      }
    }
    const float cx = coord[(size_t)n*3+0], cy = coord[(size_t)n*3+1], cz = coord[(size_t)n*3+2];
    const float ex = cent[(size_t)n*3+0],  ey = cent[(size_t)n*3+1],  ez = cent[(size_t)n*3+2];
    const float gx = ex - cx, gy = ey - cy, gz = ez - cz;
    const float dx = bx - gx, dy = by - gy, dz = bz - gz;
    const float l1 = fabsf(dx) + fabsf(dy) + fabsf(dz);
    const float npn = sqrtf(bx*bx + by*by + bz*bz) + 1e-8f;
    const float ngn = sqrtf(gx*gx + gy*gy + gz*gz) + 1e-8f;
    const float cv = -(bx*gx + by*gy + bz*gz) / (npn * ngn);
    mk = (instance[n] != -1) ? 1.f : 0.f;
    l1v = l1 * mk;
    cosv = cv * mk;
  }
  #pragma unroll
  for (int o = 32; o > 0; o >>= 1) {
    l1v  += __shfl_down(l1v, o);
    cosv += __shfl_down(cosv, o);
    mk   += __shfl_down(mk, o);
  }
  if ((tid & 63) == 0) { r0[tid>>6] = l1v; r1[tid>>6] = cosv; r2[tid>>6] = mk; }
  __syncthreads();
  if (tid == 0) {
    atomicAdd(&acc[2], r0[0]+r0[1]+r0[2]+r0[3]);
    atomicAdd(&acc[3], r1[0]+r1[1]+r1[2]+r1[3]);
    atomicAdd(&acc[4], r2[0]+r2[1]+r2[2]+r2[3]);
  }
}

__global__ __launch_bounds__(256) void assign_kernel(
    const int* __restrict__ prop_ids, const int* __restrict__ point_ids, float* __restrict__ ws)
{
  unsigned* bitmap = (unsigned*)(ws + OFF_BITMAP);
  const int i = blockIdx.x * 256 + threadIdx.x;
  if (i < M_ASSIGN) {
    const int p = prop_ids[i];
    const int n = point_ids[i];
    atomicOr(&bitmap[p * WPR + (n >> 5)], 1u << (n & 31));
  }
}

__global__ void first_kernel(const int* __restrict__ prop_ids, const int* __restrict__ point_ids,
                             float* __restrict__ ws)
{
  const int p = threadIdx.x;  // 128 threads
  int lo = 0, hi = M_ASSIGN;
  while (lo < hi) { const int mid = (lo + hi) >> 1; if (prop_ids[mid] < p) lo = mid + 1; else hi = mid; }
  if (lo > M_ASSIGN - 1) lo = M_ASSIGN - 1;
  const int* segp = (const int*)(ws + OFF_SEGPRED);
  int* ip = (int*)(ws + OFF_INSTPRED);
  ip[p] = segp[point_ids[lo]];
}

__global__ __launch_bounds__(256) void score_kernel(const float* __restrict__ ws, float* __restrict__ out)
{
  const unsigned* bitmap = (const unsigned*)(ws + OFF_BITMAP);
  const float* probs = ws + OFF_PROBS;
  const int* ip = (const int*)(ws + OFF_INSTPRED);
  __shared__ float rs[4];
  __shared__ int rc[4];
  const int p = blockIdx.x;
  const int cp = ip[p];
  const int tid = threadIdx.x;
  float s = 0.f; int cnt = 0;
  for (int w = tid; w < WPR; w += 256) {
    unsigned bits = bitmap[p * WPR + w];
    cnt += __popc(bits);
    while (bits) {
      const int b = __ffs(bits) - 1;
      bits &= bits - 1;
      const int n = (w << 5) + b;
      s += probs[(size_t)n * 20 + cp];
    }
  }
  #pragma unroll
  for (int o = 32; o > 0; o >>= 1) { s += __shfl_down(s, o); cnt += __shfl_down(cnt, o); }
  if ((tid & 63) == 0) { rs[tid>>6] = s; rc[tid>>6] = cnt; }
  __syncthreads();
  if (tid == 0) {
    const float st = rs[0]+rs[1]+rs[2]+rs[3];
    const int ct = rc[0]+rc[1]+rc[2]+rc[3];
    const bool mk = ct > 100;
    out[1 + p]   = mk ? st / (float)(ct > 1 ? ct : 1) : 0.f;
    out[129 + p] = mk ? 1.f : 0.f;
  }
}

__global__ void final_kernel(const float* __restrict__ ws, float* __restrict__ out)
{
  const float segl = ws[0] / fmaxf(ws[1], 1.f);
  const float d = ws[4] + 1e-8f;
  out[0] = segl + ws[2] / d + ws[3] / d;
}

extern "C" void kernel_launch(void* const* d_in, const int* in_sizes, int n_in,
                              void* d_out, int out_size, void* d_ws, size_t ws_size,
                              hipStream_t stream) {
  const float* feat    = (const float*)d_in[0];
  const float* coord   = (const float*)d_in[1];
  const float* cent    = (const float*)d_in[2];
  const float* w1      = (const float*)d_in[3];
  // d_in[4] = b1 : cancels through BN, unused
  const float* gamma   = (const float*)d_in[5];
  const float* beta    = (const float*)d_in[6];
  const float* w2      = (const float*)d_in[7];
  const float* b2      = (const float*)d_in[8];
  const float* seg_w   = (const float*)d_in[9];
  const float* seg_b   = (const float*)d_in[10];
  const int* segment   = (const int*)d_in[11];
  const int* instance  = (const int*)d_in[12];
  const int* prop_ids  = (const int*)d_in[13];
  const int* point_ids = (const int*)d_in[14];
  float* out = (float*)d_out;
  float* ws  = (float*)d_ws;

  // zero accumulators + BN sums + bitmap
  hipMemsetAsync(d_ws, 0, (size_t)(OFF_BITMAP + 2000000) * sizeof(float), stream);

  fused_a_kernel<<<1954, 256, 0, stream>>>(feat, w1, seg_w, seg_b, segment, ws);
  stats_kernel<<<1954, 256, 0, stream>>>(ws);
  bn_kernel<<<1, 64, 0, stream>>>(gamma, beta, ws);
  bias_loss_kernel<<<1954, 256, 0, stream>>>(coord, cent, w2, b2, instance, ws);
  assign_kernel<<<1563, 256, 0, stream>>>(prop_ids, point_ids, ws);
  first_kernel<<<1, 128, 0, stream>>>(prop_ids, point_ids, ws);
  score_kernel<<<128, 256, 0, stream>>>(ws, out);
  final_kernel<<<1, 1, 0, stream>>>(ws, out);
}